// Round 17
// baseline (115.340 us; speedup 1.0000x reference)
//
#include <hip/hip_runtime.h>
#include <hip/hip_fp16.h>

// ODEFunc CNF dynamics, B=1e6 rows, H=64:
//   h1 = elu(W1 z + b1); h2 = W2 h1 + b2; out01 = W3 elu(h2)+b3;
//   trace = sum_k elu'(h2_k) * (G ex1)_k with G[k,j]=W2[k,j]*(c_k w0_j + d_k w1_j)
//
// Ladder: R6 74 -> R8 62.5 -> R10 58 -> R11 2-tile 55.3 -> R12 f16 52 ->
// R16 consts->regs 49.5 -> R18 l2e-fold + f16 epilogue 46.5 ->
// R21 grid=512 one residency round 43.4 (BEST) -> R22 packed reduce NULL.
// Measured-null ledger: occupancy (R15), within-phase ILP (R20), reduction
// (R22). VALUBusy pinned ~52%, idle ~34%. Untested: CROSS-ITERATION pipeline.
// R23 (this): software pipeline, 1 tile/phase, ping-pong acc0/acc1:
//   phase: { prefetch z(t+2); layer1(t+1)+MFMA -> accN; epilogue(accP);
//            store t }  — epilogue reads acc completed a FULL PHASE ago
//   (no MFMA-result wait), MFMA(t+1) runs in epilogue's VALU shadow, and
//   layer1(t+1) || epilogue(t) are independent chains the compiler can
//   interleave (cross-phase ILP, not R20's more-of-same-phase).
//   Regs: acc0+acc1 = 64 AGPR (same as 2-tile), frags halve -> ~212 <= 256.
//   Static indexing: explicit 2-phase loop body (no runtime acc index).
//   Spill litmus: WRITE_SIZE must stay 11718.75 KB, FETCH ~5988 KB.
// Layouts (m120-verified): A[m=col][k=jt*32+quad*8+jj], B[k][n=col],
//   D[m=mt*16+quad*4+i][n=col].

typedef _Float16 f16x8 __attribute__((ext_vector_type(8)));
typedef _Float16 f16x2 __attribute__((ext_vector_type(2)));
typedef float    f32x4 __attribute__((ext_vector_type(4)));

static __device__ __forceinline__ f16x8 exp2_h8(f16x8 t) {
    f16x8 e;
#pragma unroll
    for (int p = 0; p < 4; ++p) {
        f16x2 t2 = {t[2*p], t[2*p+1]};
        __half2 r = h2exp2(__builtin_bit_cast(__half2, t2));
        f16x2 e2 = __builtin_bit_cast(f16x2, r);
        e[2*p] = e2[0]; e[2*p+1] = e2[1];
    }
    return e;
}

static __device__ __forceinline__ f16x2 exp2_h2(f16x2 t) {
    __half2 r = h2exp2(__builtin_bit_cast(__half2, t));
    return __builtin_bit_cast(f16x2, r);
}

static __device__ __forceinline__ f16x2 cvtpk(float a, float b) {
    return __builtin_bit_cast(f16x2, __builtin_amdgcn_cvt_pkrtz(a, b));
}

static __device__ __forceinline__ f16x2 shfl_xor_h2(f16x2 v, int m) {
    int u = __shfl_xor(__builtin_bit_cast(int, v), m);
    return __builtin_bit_cast(f16x2, u);
}

__global__ __launch_bounds__(256) __attribute__((amdgpu_waves_per_eu(2, 2)))
void odefunc_mfma(const float* __restrict__ zin,
                  const float* __restrict__ W1, const float* __restrict__ b1,
                  const float* __restrict__ W2, const float* __restrict__ b2,
                  const float* __restrict__ W3, const float* __restrict__ b3,
                  float* __restrict__ out, int B, int ntiles)
{
    const float L2E  = 1.442695040888963f;
    const float RL2E = 0.6931471805599453f;   // 1/log2(e) = ln 2

    __shared__ _Float16 sH[192];   // l2e*W1 col0 | l2e*W1 col1 | l2e*b1
    __shared__ f32x4    sC[48];    // l2e*b2 | W3row0/l2e | W3row1/l2e

    const int lane = threadIdx.x & 63;
    const int quad = lane >> 4;      // 0..3
    const int col  = lane & 15;      // row-within-tile

    if (threadIdx.x < 64) {
        int i = threadIdx.x;
        sH[i]       = (_Float16)(W1[2*i]     * L2E);
        sH[64 + i]  = (_Float16)(W1[2*i + 1] * L2E);
        sH[128 + i] = (_Float16)(b1[i]       * L2E);
        float* s = (float*)sC;
        s[i]       = b2[i] * L2E;
        s[64 + i]  = W3[i]      * RL2E;
        s[128 + i] = W3[64 + i] * RL2E;
    }

    const int wid    = blockIdx.x * (blockDim.x >> 6) + (threadIdx.x >> 6);
    const int nw     = gridDim.x * (blockDim.x >> 6);

    // ---- Loop-invariant A-fragments (f16): W2 and G (trace-folded) ----
    f16x8 aW2[4][2], aG[4][2];
#pragma unroll
    for (int mt = 0; mt < 4; ++mt) {
        const int k = mt * 16 + col;
        const float ck = W3[k], dk = W3[64 + k];
#pragma unroll
        for (int jt = 0; jt < 2; ++jt) {
            const float* p = W2 + k * 64 + jt * 32 + quad * 8;
#pragma unroll
            for (int jj = 0; jj < 8; ++jj) {
                int j = jt * 32 + quad * 8 + jj;
                float w2 = p[jj];
                aW2[mt][jt][jj] = (_Float16)w2;
                aG[mt][jt][jj]  = (_Float16)(w2 * fmaf(ck, W1[2*j], dk * W1[2*j+1]));
            }
        }
    }

    const float b30 = b3[0], b31 = b3[1];
    const f32x4 zero4 = {0.f, 0.f, 0.f, 0.f};
    const _Float16 hl2e = (_Float16)L2E;
    const _Float16 h0   = (_Float16)0.0f;
    const f16x8 zero8 = {h0,h0,h0,h0,h0,h0,h0,h0};
    const f16x8 l2e8  = {hl2e,hl2e,hl2e,hl2e,hl2e,hl2e,hl2e,hl2e};
    const f16x8 ml2e8 = {-hl2e,-hl2e,-hl2e,-hl2e,-hl2e,-hl2e,-hl2e,-hl2e};
    const f16x2 zero2 = {h0, h0};
    const f16x2 l2e2  = {hl2e, hl2e};
    const f16x2 ml2e2 = {-hl2e, -hl2e};

    __syncthreads();

    // ---- hoist per-lane constants into registers ----
    f16x8 cw0[2], cw1[2], cbb[2];
#pragma unroll
    for (int jt = 0; jt < 2; ++jt) {
        int j0 = jt * 32 + quad * 8;
        cw0[jt] = *(const f16x8*)(sH + j0);
        cw1[jt] = *(const f16x8*)(sH + j0 + 64);
        cbb[jt] = *(const f16x8*)(sH + j0 + 128);
    }
    f32x4 cb2[4];
    f16x2 cw30h[4][2], cw31h[4][2];
#pragma unroll
    for (int mt = 0; mt < 4; ++mt) {
        int k4 = mt * 4 + quad;
        cb2[mt] = sC[k4];
        f32x4 w30 = sC[k4 + 16];
        f32x4 w31 = sC[k4 + 32];
        cw30h[mt][0] = cvtpk(w30[0], w30[1]);
        cw30h[mt][1] = cvtpk(w30[2], w30[3]);
        cw31h[mt][0] = cvtpk(w31[0], w31[1]);
        cw31h[mt][1] = cvtpk(w31[2], w31[3]);
    }

    const int lload = lane < 48 ? lane : 47;

    struct Acc { f32x4 H[4]; f32x4 T[4]; };
    Acc acc0, acc1;

    // layer-1 + MFMA for one tile (front of the pipeline)
    auto tile_compute = [&](float zvt, Acc& ac) {
        float z0 = __shfl(zvt, 3 * col), z1 = __shfl(zvt, 3 * col + 1);
        const _Float16 z0h = (_Float16)z0, z1h = (_Float16)z1;
        const f16x8 z08 = {z0h,z0h,z0h,z0h,z0h,z0h,z0h,z0h};
        const f16x8 z18 = {z1h,z1h,z1h,z1h,z1h,z1h,z1h,z1h};
        f16x8 Bh[2], Be[2];
#pragma unroll
        for (int jt = 0; jt < 2; ++jt) {
            f16x8 a = __builtin_elementwise_fma(cw0[jt], z08,
                      __builtin_elementwise_fma(cw1[jt], z18, cbb[jt]));
            f16x8 e = exp2_h8(__builtin_elementwise_min(a, zero8));
            Bh[jt] = __builtin_elementwise_max(a,
                     __builtin_elementwise_fma(l2e8, e, ml2e8));
            Be[jt] = e;
        }
#pragma unroll
        for (int mt = 0; mt < 4; ++mt) {
            ac.H[mt] = __builtin_amdgcn_mfma_f32_16x16x32_f16(aW2[mt][0], Bh[0], cb2[mt], 0, 0, 0);
            ac.H[mt] = __builtin_amdgcn_mfma_f32_16x16x32_f16(aW2[mt][1], Bh[1], ac.H[mt], 0, 0, 0);
            ac.T[mt] = __builtin_amdgcn_mfma_f32_16x16x32_f16(aG[mt][0], Be[0], zero4, 0, 0, 0);
            ac.T[mt] = __builtin_amdgcn_mfma_f32_16x16x32_f16(aG[mt][1], Be[1], ac.T[mt], 0, 0, 0);
        }
    };

    // epilogue + reduce + store for one tile (back of the pipeline)
    auto tile_finish = [&](Acc& ac, int tt) {
        f16x2 o02 = zero2, o12 = zero2, tr2 = zero2;
#pragma unroll
        for (int mt = 0; mt < 4; ++mt) {
#pragma unroll
            for (int p = 0; p < 2; ++p) {
                f16x2 ah = cvtpk(ac.H[mt][2*p], ac.H[mt][2*p+1]);
                f16x2 at = cvtpk(ac.T[mt][2*p], ac.T[mt][2*p+1]);
                f16x2 e  = exp2_h2(__builtin_elementwise_min(ah, zero2));
                f16x2 hh = __builtin_elementwise_max(ah,
                           __builtin_elementwise_fma(l2e2, e, ml2e2));
                o02 = __builtin_elementwise_fma(cw30h[mt][p], hh, o02);
                o12 = __builtin_elementwise_fma(cw31h[mt][p], hh, o12);
                tr2 = __builtin_elementwise_fma(e, at, tr2);
            }
        }
        f16x2 po = { (_Float16)(o02[0] + o02[1]), (_Float16)(o12[0] + o12[1]) };
        f16x2 pt = { (_Float16)(tr2[0] + tr2[1]), h0 };
        po += shfl_xor_h2(po, 16);  po += shfl_xor_h2(po, 32);
        pt += shfl_xor_h2(pt, 16);  pt += shfl_xor_h2(pt, 32);
        int row = tt * 16 + col;
        if (lane < 16 && row < B) {
            out[3 * row + 0] = (float)po[0] + b30;
            out[3 * row + 1] = (float)po[1] + b31;
            out[3 * row + 2] = -(float)pt[0];
        }
    };

    // ---- software-pipelined main loop (2-phase ping-pong, static indices) ----
    int t = wid;                                   // wid < ntiles (2048 << 62500)
    float zcur = zin[t * 48 + lload];
    int tn0 = t + nw;
    float znext = zin[(tn0 < ntiles ? tn0 : 0) * 48 + lload];
    tile_compute(zcur, acc0);                      // fill pipeline: tile t

    while (true) {
        // phase 0: acc0 ready (tile t); znext = z(t+nw)
        int t2 = t + 2 * nw;
        zcur = zin[(t2 < ntiles ? t2 : 0) * 48 + lload];   // prefetch z(t+2nw)
        tile_compute(znext, acc1);                 // front: tile t+nw
        tile_finish(acc0, t);                      // back:  tile t (acc ready long ago)
        if (t + nw >= ntiles) break;
        // phase 1: acc1 ready (tile t+nw); zcur = z(t+2nw)
        int t3 = t + 3 * nw;
        znext = zin[(t3 < ntiles ? t3 : 0) * 48 + lload];  // prefetch z(t+3nw)
        tile_compute(zcur, acc0);                  // front: tile t+2nw
        tile_finish(acc1, t + nw);                 // back:  tile t+nw
        if (t2 >= ntiles) break;
        t = t2;
    }
}

extern "C" void kernel_launch(void* const* d_in, const int* in_sizes, int n_in,
                              void* d_out, int out_size, void* d_ws, size_t ws_size,
                              hipStream_t stream) {
    // d_in: 0=t(unused) 1=z_and_logp 2=W1 3=b1 4=W2 5=b2 6=W3 7=b3
    const float* zin = (const float*)d_in[1];
    const float* W1  = (const float*)d_in[2];
    const float* b1  = (const float*)d_in[3];
    const float* W2  = (const float*)d_in[4];
    const float* b2  = (const float*)d_in[5];
    const float* W3  = (const float*)d_in[6];
    const float* b3  = (const float*)d_in[7];
    float* out = (float*)d_out;

    int B = in_sizes[1] / 3;
    int ntiles = (B + 15) / 16;
    int grid = 512;   // 2048 waves = one residency round (R21 win)
    odefunc_mfma<<<grid, 256, 0, stream>>>(zin, W1, b1, W2, b2, W3, b3,
                                           out, B, ntiles);
}

// Round 18
// 112.959 us; speedup vs baseline: 1.0211x; 1.0211x over previous
//
#include <hip/hip_runtime.h>
#include <hip/hip_fp16.h>

// ODEFunc CNF dynamics, B=1e6 rows, H=64:
//   h1 = elu(W1 z + b1); h2 = W2 h1 + b2; out01 = W3 elu(h2)+b3;
//   trace = sum_k elu'(h2_k) * (G ex1)_k with G[k,j]=W2[k,j]*(c_k w0_j + d_k w1_j)
//
// Ladder: R6 74 -> R8 62.5 -> R10 58 -> R11 2-tile 55.3 -> R12 f16 52 ->
// R16 consts->regs 49.5 -> R18 l2e-fold + f16 epilogue 46.5 ->
// R21 grid=512 one residency round 43.4 (BEST) -> R22 packed reduce null ->
// R23 sw-pipeline NEGATIVE 45.5 (2-tile already has cross-phase slack).
// Null ledger: occupancy (R15), ILP (R20), pipeline (R23), reduction (R22).
// Per-wave issue only ~26% of cycles; one serial-latency block left at loop
// head: 4x __shfl z-broadcast (DS pipe ~50cyc each, layer-1 depends on them).
// They exist ONLY because the coalesced load puts row r's z in lane 3r —
// but the fragment layout gives each lane its own row (n=col) anyway.
// R24 (this): direct per-lane z loads, prefetched one iteration ahead:
//   z0 = zin[3*(t*16+col)], z1 = zin[.+1] — zero cross-lane traffic; quads
//   read the same 192B region (L1-served); ~3400cyc of prefetch cover.
//   Removes 4 serial DS ops/pair from the critical path + lload machinery.
//   Spill litmus: WRITE_SIZE must stay 11718.75 KB; FETCH ~5985-6100 KB ok.
// Layouts (m120-verified): A[m=col][k=jt*32+quad*8+jj], B[k][n=col],
//   D[m=mt*16+quad*4+i][n=col].

typedef _Float16 f16x8 __attribute__((ext_vector_type(8)));
typedef _Float16 f16x2 __attribute__((ext_vector_type(2)));
typedef float    f32x4 __attribute__((ext_vector_type(4)));

static __device__ __forceinline__ f16x8 exp2_h8(f16x8 t) {
    f16x8 e;
#pragma unroll
    for (int p = 0; p < 4; ++p) {
        f16x2 t2 = {t[2*p], t[2*p+1]};
        __half2 r = h2exp2(__builtin_bit_cast(__half2, t2));
        f16x2 e2 = __builtin_bit_cast(f16x2, r);
        e[2*p] = e2[0]; e[2*p+1] = e2[1];
    }
    return e;
}

static __device__ __forceinline__ f16x2 exp2_h2(f16x2 t) {
    __half2 r = h2exp2(__builtin_bit_cast(__half2, t));
    return __builtin_bit_cast(f16x2, r);
}

static __device__ __forceinline__ f16x2 cvtpk(float a, float b) {
    return __builtin_bit_cast(f16x2, __builtin_amdgcn_cvt_pkrtz(a, b));
}

static __device__ __forceinline__ f16x2 shfl_xor_h2(f16x2 v, int m) {
    int u = __shfl_xor(__builtin_bit_cast(int, v), m);
    return __builtin_bit_cast(f16x2, u);
}

__global__ __launch_bounds__(256) __attribute__((amdgpu_waves_per_eu(2, 2)))
void odefunc_mfma(const float* __restrict__ zin,
                  const float* __restrict__ W1, const float* __restrict__ b1,
                  const float* __restrict__ W2, const float* __restrict__ b2,
                  const float* __restrict__ W3, const float* __restrict__ b3,
                  float* __restrict__ out, int B, int ntiles)
{
    const float L2E  = 1.442695040888963f;
    const float RL2E = 0.6931471805599453f;   // 1/log2(e) = ln 2

    __shared__ _Float16 sH[192];   // l2e*W1 col0 | l2e*W1 col1 | l2e*b1
    __shared__ f32x4    sC[48];    // l2e*b2 | W3row0/l2e | W3row1/l2e

    const int lane = threadIdx.x & 63;
    const int quad = lane >> 4;      // 0..3
    const int col  = lane & 15;      // row-within-tile

    if (threadIdx.x < 64) {
        int i = threadIdx.x;
        sH[i]       = (_Float16)(W1[2*i]     * L2E);
        sH[64 + i]  = (_Float16)(W1[2*i + 1] * L2E);
        sH[128 + i] = (_Float16)(b1[i]       * L2E);
        float* s = (float*)sC;
        s[i]       = b2[i] * L2E;
        s[64 + i]  = W3[i]      * RL2E;
        s[128 + i] = W3[64 + i] * RL2E;
    }

    const int wid    = blockIdx.x * (blockDim.x >> 6) + (threadIdx.x >> 6);
    const int nwaves = gridDim.x * (blockDim.x >> 6);

    // ---- Loop-invariant A-fragments (f16): W2 and G (trace-folded) ----
    f16x8 aW2[4][2], aG[4][2];
#pragma unroll
    for (int mt = 0; mt < 4; ++mt) {
        const int k = mt * 16 + col;
        const float ck = W3[k], dk = W3[64 + k];
#pragma unroll
        for (int jt = 0; jt < 2; ++jt) {
            const float* p = W2 + k * 64 + jt * 32 + quad * 8;
#pragma unroll
            for (int jj = 0; jj < 8; ++jj) {
                int j = jt * 32 + quad * 8 + jj;
                float w2 = p[jj];
                aW2[mt][jt][jj] = (_Float16)w2;
                aG[mt][jt][jj]  = (_Float16)(w2 * fmaf(ck, W1[2*j], dk * W1[2*j+1]));
            }
        }
    }

    const float b30 = b3[0], b31 = b3[1];
    const f32x4 zero4 = {0.f, 0.f, 0.f, 0.f};
    const _Float16 hl2e = (_Float16)L2E;
    const _Float16 h0   = (_Float16)0.0f;
    const f16x8 zero8 = {h0,h0,h0,h0,h0,h0,h0,h0};
    const f16x8 l2e8  = {hl2e,hl2e,hl2e,hl2e,hl2e,hl2e,hl2e,hl2e};
    const f16x8 ml2e8 = {-hl2e,-hl2e,-hl2e,-hl2e,-hl2e,-hl2e,-hl2e,-hl2e};
    const f16x2 zero2 = {h0, h0};
    const f16x2 l2e2  = {hl2e, hl2e};
    const f16x2 ml2e2 = {-hl2e, -hl2e};

    __syncthreads();

    // ---- hoist per-lane constants into registers ----
    f16x8 cw0[2], cw1[2], cbb[2];
#pragma unroll
    for (int jt = 0; jt < 2; ++jt) {
        int j0 = jt * 32 + quad * 8;
        cw0[jt] = *(const f16x8*)(sH + j0);
        cw1[jt] = *(const f16x8*)(sH + j0 + 64);
        cbb[jt] = *(const f16x8*)(sH + j0 + 128);
    }
    f32x4 cb2[4];
    f16x2 cw30h[4][2], cw31h[4][2];
#pragma unroll
    for (int mt = 0; mt < 4; ++mt) {
        int k4 = mt * 4 + quad;
        cb2[mt] = sC[k4];
        f32x4 w30 = sC[k4 + 16];
        f32x4 w31 = sC[k4 + 32];
        cw30h[mt][0] = cvtpk(w30[0], w30[1]);
        cw30h[mt][1] = cvtpk(w30[2], w30[3]);
        cw31h[mt][0] = cvtpk(w31[0], w31[1]);
        cw31h[mt][1] = cvtpk(w31[2], w31[3]);
    }

    // ---- direct per-lane z: lane needs only its own row's (z0,z1) ----
    // row = t*16 + col; quads read the same 192B region (L1-served).
    int tp = wid;                     // tile-pair index: tiles 2tp, 2tp+1
    float z0A = 0.f, z1A = 0.f, z0B = 0.f, z1B = 0.f;
    if (2 * tp < ntiles) {
        int rA = (2 * tp) * 16 + col;
        z0A = zin[3 * rA];  z1A = zin[3 * rA + 1];
        if (2 * tp + 1 < ntiles) {
            int rB = (2 * tp + 1) * 16 + col;
            z0B = zin[3 * rB];  z1B = zin[3 * rB + 1];
        }
    }

    for (; 2 * tp < ntiles; tp += nwaves) {
        const int tA = 2 * tp, tB = 2 * tp + 1;
        const bool vB = tB < ntiles;

        // prefetch next pair's z (direct per-lane; ~3400cyc of cover)
        int tpn = tp + nwaves;
        int rAn = ((2 * tpn     < ntiles) ? 2 * tpn     : 0) * 16 + col;
        int rBn = ((2 * tpn + 1 < ntiles) ? 2 * tpn + 1 : 0) * 16 + col;
        float z0An = zin[3 * rAn], z1An = zin[3 * rAn + 1];
        float z0Bn = zin[3 * rBn], z1Bn = zin[3 * rBn + 1];

        const _Float16 z0Ah = (_Float16)z0A, z1Ah = (_Float16)z1A;
        const _Float16 z0Bh = (_Float16)z0B, z1Bh = (_Float16)z1B;
        const f16x8 z0A8 = {z0Ah,z0Ah,z0Ah,z0Ah,z0Ah,z0Ah,z0Ah,z0Ah};
        const f16x8 z1A8 = {z1Ah,z1Ah,z1Ah,z1Ah,z1Ah,z1Ah,z1Ah,z1Ah};
        const f16x8 z0B8 = {z0Bh,z0Bh,z0Bh,z0Bh,z0Bh,z0Bh,z0Bh,z0Bh};
        const f16x8 z1B8 = {z1Bh,z1Bh,z1Bh,z1Bh,z1Bh,z1Bh,z1Bh,z1Bh};

        // ---- layer 1: a' = l2e*a (pre-scaled consts); e = exp2(min(a',0));
        //      Bh' = l2e*elu(a) = max(a', fma(l2e,e,-l2e)) ----
        f16x8 BhA[2], BeA[2], BhB[2], BeB[2];
#pragma unroll
        for (int jt = 0; jt < 2; ++jt) {
            // tile A
            f16x8 aA = __builtin_elementwise_fma(cw0[jt], z0A8,
                       __builtin_elementwise_fma(cw1[jt], z1A8, cbb[jt]));
            f16x8 eA = exp2_h8(__builtin_elementwise_min(aA, zero8));
            f16x8 hA = __builtin_elementwise_max(aA,
                       __builtin_elementwise_fma(l2e8, eA, ml2e8));
            // tile B (independent chain)
            f16x8 aB = __builtin_elementwise_fma(cw0[jt], z0B8,
                       __builtin_elementwise_fma(cw1[jt], z1B8, cbb[jt]));
            f16x8 eB = exp2_h8(__builtin_elementwise_min(aB, zero8));
            f16x8 hB = __builtin_elementwise_max(aB,
                       __builtin_elementwise_fma(l2e8, eB, ml2e8));
            BhA[jt] = hA; BeA[jt] = eA;
            BhB[jt] = hB; BeB[jt] = eB;
        }

        // ---- MFMA: accH = W2*(l2e*h) + l2e*b2 = l2e*h2pre; accT = G*e ----
        f32x4 aHA[4], aTA[4], aHB[4], aTB[4];
#pragma unroll
        for (int mt = 0; mt < 4; ++mt) {
            aHA[mt] = __builtin_amdgcn_mfma_f32_16x16x32_f16(aW2[mt][0], BhA[0], cb2[mt], 0, 0, 0);
            aHA[mt] = __builtin_amdgcn_mfma_f32_16x16x32_f16(aW2[mt][1], BhA[1], aHA[mt], 0, 0, 0);
            aHB[mt] = __builtin_amdgcn_mfma_f32_16x16x32_f16(aW2[mt][0], BhB[0], cb2[mt], 0, 0, 0);
            aHB[mt] = __builtin_amdgcn_mfma_f32_16x16x32_f16(aW2[mt][1], BhB[1], aHB[mt], 0, 0, 0);
            aTA[mt] = __builtin_amdgcn_mfma_f32_16x16x32_f16(aG[mt][0], BeA[0], zero4, 0, 0, 0);
            aTA[mt] = __builtin_amdgcn_mfma_f32_16x16x32_f16(aG[mt][1], BeA[1], aTA[mt], 0, 0, 0);
            aTB[mt] = __builtin_amdgcn_mfma_f32_16x16x32_f16(aG[mt][0], BeB[0], zero4, 0, 0, 0);
            aTB[mt] = __builtin_amdgcn_mfma_f32_16x16x32_f16(aG[mt][1], BeB[1], aTB[mt], 0, 0, 0);
        }

        // ---- epilogue (packed f16): e2 = exp2(min(acc,0));
        //      hh' = max(acc, fma(l2e,e2,-l2e)); folds in pk_fma_f16 ----
        f16x2 o0A2 = zero2, o1A2 = zero2, trA2 = zero2;
        f16x2 o0B2 = zero2, o1B2 = zero2, trB2 = zero2;
#pragma unroll
        for (int mt = 0; mt < 4; ++mt) {
#pragma unroll
            for (int p = 0; p < 2; ++p) {
                f16x2 w30p = cw30h[mt][p], w31p = cw31h[mt][p];
                // tile A
                f16x2 ahA = cvtpk(aHA[mt][2*p], aHA[mt][2*p+1]);
                f16x2 atA = cvtpk(aTA[mt][2*p], aTA[mt][2*p+1]);
                f16x2 eA  = exp2_h2(__builtin_elementwise_min(ahA, zero2));
                f16x2 hhA = __builtin_elementwise_max(ahA,
                            __builtin_elementwise_fma(l2e2, eA, ml2e2));
                o0A2 = __builtin_elementwise_fma(w30p, hhA, o0A2);
                o1A2 = __builtin_elementwise_fma(w31p, hhA, o1A2);
                trA2 = __builtin_elementwise_fma(eA, atA, trA2);
                // tile B
                f16x2 ahB = cvtpk(aHB[mt][2*p], aHB[mt][2*p+1]);
                f16x2 atB = cvtpk(aTB[mt][2*p], aTB[mt][2*p+1]);
                f16x2 eB  = exp2_h2(__builtin_elementwise_min(ahB, zero2));
                f16x2 hhB = __builtin_elementwise_max(ahB,
                            __builtin_elementwise_fma(l2e2, eB, ml2e2));
                o0B2 = __builtin_elementwise_fma(w30p, hhB, o0B2);
                o1B2 = __builtin_elementwise_fma(w31p, hhB, o1B2);
                trB2 = __builtin_elementwise_fma(eB, atB, trB2);
            }
        }

        // ---- packed f16x2 cross-quad reduction (R22) ----
        f16x2 pA  = { (_Float16)(o0A2[0] + o0A2[1]), (_Float16)(o1A2[0] + o1A2[1]) };
        f16x2 pB  = { (_Float16)(o0B2[0] + o0B2[1]), (_Float16)(o1B2[0] + o1B2[1]) };
        f16x2 pT  = { (_Float16)(trA2[0] + trA2[1]), (_Float16)(trB2[0] + trB2[1]) };
        pA += shfl_xor_h2(pA, 16);  pA += shfl_xor_h2(pA, 32);
        pB += shfl_xor_h2(pB, 16);  pB += shfl_xor_h2(pB, 32);
        pT += shfl_xor_h2(pT, 16);  pT += shfl_xor_h2(pT, 32);

        int rowA = tA * 16 + col;
        if (lane < 16 && rowA < B) {
            out[3 * rowA + 0] = (float)pA[0] + b30;
            out[3 * rowA + 1] = (float)pA[1] + b31;
            out[3 * rowA + 2] = -(float)pT[0];
        }
        int rowB = tB * 16 + col;
        if (lane < 16 && vB && rowB < B) {
            out[3 * rowB + 0] = (float)pB[0] + b30;
            out[3 * rowB + 1] = (float)pB[1] + b31;
            out[3 * rowB + 2] = -(float)pT[1];
        }

        z0A = z0An; z1A = z1An;
        z0B = z0Bn; z1B = z1Bn;
    }
}

extern "C" void kernel_launch(void* const* d_in, const int* in_sizes, int n_in,
                              void* d_out, int out_size, void* d_ws, size_t ws_size,
                              hipStream_t stream) {
    // d_in: 0=t(unused) 1=z_and_logp 2=W1 3=b1 4=W2 5=b2 6=W3 7=b3
    const float* zin = (const float*)d_in[1];
    const float* W1  = (const float*)d_in[2];
    const float* b1  = (const float*)d_in[3];
    const float* W2  = (const float*)d_in[4];
    const float* b2  = (const float*)d_in[5];
    const float* W3  = (const float*)d_in[6];
    const float* b3  = (const float*)d_in[7];
    float* out = (float*)d_out;

    int B = in_sizes[1] / 3;
    int ntiles = (B + 15) / 16;
    int grid = 512;   // 2048 waves = one residency round (R21 win)
    odefunc_mfma<<<grid, 256, 0, stream>>>(zin, W1, b1, W2, b2, W3, b3,
                                           out, B, ntiles);
}